// Round 2
// baseline (916.410 us; speedup 1.0000x reference)
//
#include <hip/hip_runtime.h>

#define NB 16
#define NS 256
#define LO 128
#define NLAB (LO * LO)
#define LOG2E 1.4426950408889634f
#define LN2f 0.6931471805599453f

typedef const __attribute__((address_space(1))) void gas_void;
typedef __attribute__((address_space(3))) void las_void;

__device__ __forceinline__ void gload16(const void* g, void* l) {
    // 16B per lane, wave-uniform LDS base + lane*16 (HW semantics)
    __builtin_amdgcn_global_load_lds((gas_void*)g, (las_void*)l, 16, 0, 0);
}

// One workgroup per batch. 1024 threads = 16 waves.
// LDS: double-buffered 64KB emission tile + alpha (log2-scaled) + partials.
__global__ __launch_bounds__(1024) void crf_fwd(
    const float* __restrict__ emits,   // [B, S, NLAB] fp32
    const int* __restrict__ targets,   // [B, S] int32
    const int* __restrict__ mask,      // [B, S] int32 (bool normalized)
    float* __restrict__ out)           // out[0] += (logz_b - gold_b)/total
{
    __shared__ float ebuf[2][NLAB];   // 2 x 64KB
    __shared__ float alpha2[LO];      // alpha_hat * log2e
    __shared__ float psum[8 * LO];    // partial exp-sums [group][j]
    __shared__ float wred[16];        // cross-wave reduction scratch
    __shared__ float stot;            // global token count

    const int b = blockIdx.x;
    const int t = threadIdx.x;
    const int lane = t & 63;
    const int w = t >> 6;     // wave id 0..15
    const int g = t >> 7;     // i-group 0..7
    const int j = t & 127;    // output column
    const float* eb = emits + (size_t)b * NS * NLAB;

    // ---- prologue: prefetch E_1 into buf0 (overlaps with everything below) ----
    {
        const float* src = eb + NLAB; // s = 1
        #pragma unroll
        for (int k = 0; k < 4; ++k) {
            const int c = w * 4 + k;                 // 64 chunks of 256 floats
            gload16(src + c * 256 + lane * 4, &ebuf[0][c * 256]);
        }
    }

    // ---- global token count (every block computes the same value) ----
    {
        float cnt = 0.f;
        for (int idx = t; idx < NB * NS; idx += 1024) cnt += mask[idx] ? 1.f : 0.f;
        #pragma unroll
        for (int off = 32; off; off >>= 1) cnt += __shfl_xor(cnt, off);
        if (lane == 0) wred[w] = cnt;
        __syncthreads();
        if (t == 0) {
            float tt = 0.f;
            #pragma unroll
            for (int k = 0; k < 16; ++k) tt += wred[k];
            stot = tt;
        }
        __syncthreads();
    }

    // ---- init: alpha0[j] = emits[b,0,BOS*LO + j], BOS = 0 ----
    float M = 0.f;
    float goldacc = 0.f;
    {
        float a0 = (t < LO) ? eb[j] : -1e30f;
        float m = a0;
        if (t < LO) {
            #pragma unroll
            for (int off = 32; off; off >>= 1) m = fmaxf(m, __shfl_xor(m, off));
            if (lane == 0) wred[w] = m;
        }
        __syncthreads();
        const float mx = fmaxf(wred[0], wred[1]);
        M = mx;
        if (t < LO) alpha2[j] = (a0 - mx) * LOG2E;
        if (t == 0 && mask[b * NS]) goldacc += eb[targets[b * NS]];
        __syncthreads();
    }

    // ---- main sequential chain ----
    for (int s = 1; s < NS; ++s) {
        const int cur = (s + 1) & 1;  // buffer holding E_s
        const int nxt = s & 1;

        // prefetch E_{s+1}; completes by the first __syncthreads (vmcnt drain)
        if (s + 1 < NS) {
            const float* src = eb + (size_t)(s + 1) * NLAB;
            #pragma unroll
            for (int k = 0; k < 4; ++k) {
                const int c = w * 4 + k;
                gload16(src + c * 256 + lane * 4, &ebuf[nxt][c * 256]);
            }
        }

        const bool msk = mask[b * NS + s] != 0;

        // partial exp-sums: group g covers i in [16g, 16g+16)
        {
            const float* E = ebuf[cur];
            const int base = (g * 16) * LO + j;
            float ls = 0.f;
            #pragma unroll
            for (int ii = 0; ii < 16; ++ii) {
                const float x = fmaf(E[base + ii * LO], LOG2E, alpha2[g * 16 + ii]);
                ls += __builtin_amdgcn_exp2f(x);
            }
            psum[g * LO + j] = ls;
        }
        __syncthreads();  // psum visible; also drains the prefetch

        float tj = 0.f;
        if (t < LO) {
            float ssum = 0.f;
            #pragma unroll
            for (int gg = 0; gg < 8; ++gg) ssum += psum[gg * LO + j];
            tj = __builtin_amdgcn_logf(ssum) * LN2f;  // v_log_f32 is log2 -> ln
            float m2 = tj;
            #pragma unroll
            for (int off = 32; off; off >>= 1) m2 = fmaxf(m2, __shfl_xor(m2, off));
            if (lane == 0) wred[w] = m2;
        }
        __syncthreads();

        if (msk) {
            const float mx2 = fmaxf(wred[0], wred[1]);
            M += mx2;
            if (t < LO) alpha2[j] = (tj - mx2) * LOG2E;
        }
        if (t == 0 && msk) goldacc += ebuf[cur][targets[b * NS + s]];
        __syncthreads();  // protect alpha2/wred/ebuf[cur] before next iteration
    }

    // ---- final logsumexp over j + batch contribution ----
    {
        float fe = (t < LO) ? __builtin_amdgcn_exp2f(alpha2[j]) : 0.f;
        if (t < LO) {
            #pragma unroll
            for (int off = 32; off; off >>= 1) fe += __shfl_xor(fe, off);
            if (lane == 0) wred[w] = fe;
        }
        __syncthreads();
        if (t == 0) {
            const float logz = M + __builtin_amdgcn_logf(wred[0] + wred[1]) * LN2f;
            atomicAdd(out, (logz - goldacc) / stot);
        }
    }
}

extern "C" void kernel_launch(void* const* d_in, const int* in_sizes, int n_in,
                              void* d_out, int out_size, void* d_ws, size_t ws_size,
                              hipStream_t stream) {
    (void)in_sizes; (void)n_in; (void)out_size; (void)d_ws; (void)ws_size;
    const float* emits = (const float*)d_in[0];
    const int* targets = (const int*)d_in[1];
    const int* mask = (const int*)d_in[2];

    hipMemsetAsync(d_out, 0, sizeof(float), stream);
    hipLaunchKernelGGL(crf_fwd, dim3(NB), dim3(1024), 0, stream,
                       emits, targets, mask, (float*)d_out);
}

// Round 3
// 657.331 us; speedup vs baseline: 1.3941x; 1.3941x over previous
//
#include <hip/hip_runtime.h>

#define NB 16
#define NS 256
#define LO 128
#define NLAB (LO * LO)
#define LOG2E 1.4426950408889634f
#define LN2f 0.6931471805599453f

typedef float f4 __attribute__((ext_vector_type(4)));

// barrier with LDS-write visibility, WITHOUT draining vmcnt (keeps E prefetch in flight)
__device__ __forceinline__ void bar_lgkm() {
    asm volatile("s_waitcnt lgkmcnt(0)" ::: "memory");
    __builtin_amdgcn_s_barrier();
}

// One step: compute psum from C-regs, prefetch step PS into N-regs, reduce+update alpha.
// ig = t>>5 (4-row group), jb = t&31 (4-col block). Wave 0 owns the column reduce.
#define CRF_STEP(C0, C1, C2, C3, N0, N1, N2, N3, S, PREF)                      \
    {                                                                          \
        if (PREF) {                                                            \
            const f4* p_ = ef + (size_t)((S) + 1) * 4096 + base;               \
            N0 = p_[0]; N1 = p_[32]; N2 = p_[64]; N3 = p_[96];                 \
        }                                                                      \
        float a0_ = 0.f, a1_ = 0.f, a2_ = 0.f, a3_ = 0.f;                      \
        {                                                                      \
            f4 e_ = C0;                                                        \
            a0_ += __builtin_amdgcn_exp2f(__builtin_fmaf(e_.x, LOG2E, ar0));   \
            a1_ += __builtin_amdgcn_exp2f(__builtin_fmaf(e_.y, LOG2E, ar0));   \
            a2_ += __builtin_amdgcn_exp2f(__builtin_fmaf(e_.z, LOG2E, ar0));   \
            a3_ += __builtin_amdgcn_exp2f(__builtin_fmaf(e_.w, LOG2E, ar0));   \
            e_ = C1;                                                           \
            a0_ += __builtin_amdgcn_exp2f(__builtin_fmaf(e_.x, LOG2E, ar1));   \
            a1_ += __builtin_amdgcn_exp2f(__builtin_fmaf(e_.y, LOG2E, ar1));   \
            a2_ += __builtin_amdgcn_exp2f(__builtin_fmaf(e_.z, LOG2E, ar1));   \
            a3_ += __builtin_amdgcn_exp2f(__builtin_fmaf(e_.w, LOG2E, ar1));   \
            e_ = C2;                                                           \
            a0_ += __builtin_amdgcn_exp2f(__builtin_fmaf(e_.x, LOG2E, ar2));   \
            a1_ += __builtin_amdgcn_exp2f(__builtin_fmaf(e_.y, LOG2E, ar2));   \
            a2_ += __builtin_amdgcn_exp2f(__builtin_fmaf(e_.z, LOG2E, ar2));   \
            a3_ += __builtin_amdgcn_exp2f(__builtin_fmaf(e_.w, LOG2E, ar2));   \
            e_ = C3;                                                           \
            a0_ += __builtin_amdgcn_exp2f(__builtin_fmaf(e_.x, LOG2E, ar3));   \
            a1_ += __builtin_amdgcn_exp2f(__builtin_fmaf(e_.y, LOG2E, ar3));   \
            a2_ += __builtin_amdgcn_exp2f(__builtin_fmaf(e_.z, LOG2E, ar3));   \
            a3_ += __builtin_amdgcn_exp2f(__builtin_fmaf(e_.w, LOG2E, ar3));   \
        }                                                                      \
        f4 ps_; ps_.x = a0_; ps_.y = a1_; ps_.z = a2_; ps_.w = a3_;            \
        *(f4*)&psum[ig * LO + jb * 4] = ps_;                                   \
        bar_lgkm(); /* B1: psum visible; E prefetch stays in flight */         \
        if (w == 0) {                                                          \
            float s1_ = 0.f, s2_ = 0.f;                                        \
            _Pragma("unroll")                                                  \
            for (int g_ = 0; g_ < 32; ++g_) {                                  \
                s1_ += psum[g_ * LO + lane];                                   \
                s2_ += psum[g_ * LO + 64 + lane];                              \
            }                                                                  \
            float t1_ = __builtin_amdgcn_logf(s1_);  /* v_log_f32 = log2 */    \
            float t2_ = __builtin_amdgcn_logf(s2_);                            \
            if (maskL[S]) {                                                    \
                float mx_ = fmaxf(t1_, t2_);                                   \
                _Pragma("unroll")                                              \
                for (int off_ = 32; off_; off_ >>= 1)                          \
                    mx_ = fmaxf(mx_, __shfl_xor(mx_, off_));                   \
                M2 += mx_;                                                     \
                alpha2[lane] = t1_ - mx_;                                      \
                alpha2[lane + 64] = t2_ - mx_;                                 \
            }                                                                  \
        }                                                                      \
        bar_lgkm(); /* B2: alpha2 visible */                                   \
        { f4 av_ = *(const f4*)&alpha2[ig * 4];                                \
          ar0 = av_.x; ar1 = av_.y; ar2 = av_.z; ar3 = av_.w; }                \
    }

__global__ __launch_bounds__(1024, 4) void crf_fwd(
    const float* __restrict__ emits,   // [B, S, NLAB] fp32
    const int* __restrict__ targets,   // [B, S] int32
    const int* __restrict__ mask,      // [B, S] int32
    float* __restrict__ out)
{
    __shared__ float psum[32 * LO];   // 16 KB: [ig][j]
    __shared__ float alpha2[LO];      // log2-domain, max-shifted
    __shared__ float wred[16];
    __shared__ int maskL[NS];
    __shared__ float sgold, stot;

    const int b = blockIdx.x;
    const int t = threadIdx.x;
    const int lane = t & 63;
    const int w = t >> 6;
    const int jb = t & 31;    // 4-column block
    const int ig = t >> 5;    // 4-row group (0..31)
    const float* eb = emits + (size_t)b * NS * NLAB;
    const f4* ef = (const f4*)eb;
    const int base = ig * 128 + jb;   // f4 index of (row 4ig, col 4jb)

    f4 eA0, eA1, eA2, eA3, eB0, eB1, eB2, eB3;

    // ---- prefetch E_1 into A-regs immediately ----
    {
        const f4* p_ = ef + (size_t)4096 + base;
        eA0 = p_[0]; eA1 = p_[32]; eA2 = p_[64]; eA3 = p_[96];
    }

    // ---- prologue: mask stage + token count ----
    float cnt = 0.f;
    for (int idx = t; idx < NB * NS; idx += 1024) cnt += mask[idx] ? 1.f : 0.f;
    #pragma unroll
    for (int off = 32; off; off >>= 1) cnt += __shfl_xor(cnt, off);
    if (lane == 0) wred[w] = cnt;
    if (t < NS) maskL[t] = mask[b * NS + t];
    __syncthreads();
    if (t == 0) {
        float s_ = 0.f;
        #pragma unroll
        for (int k = 0; k < 16; ++k) s_ += wred[k];
        stot = s_;
    }
    __syncthreads();

    // ---- gold scores (all steps, gathered from global once) ----
    float gv = 0.f;
    if (t < NS && maskL[t]) gv = eb[(size_t)t * NLAB + targets[b * NS + t]];
    #pragma unroll
    for (int off = 32; off; off >>= 1) gv += __shfl_xor(gv, off);
    if (lane == 0 && w < 4) wred[w] = gv;

    // ---- alpha init (BOS row 0 of E_0), wave 0 only, log2 domain ----
    float M2 = 0.f;
    float ar0, ar1, ar2, ar3;
    __syncthreads();
    if (t == 0) sgold = wred[0] + wred[1] + wred[2] + wred[3];
    if (w == 0) {
        float l1 = eb[lane] * LOG2E;
        float l2 = eb[lane + 64] * LOG2E;
        float mx = fmaxf(l1, l2);
        #pragma unroll
        for (int off = 32; off; off >>= 1) mx = fmaxf(mx, __shfl_xor(mx, off));
        M2 = mx;
        alpha2[lane] = l1 - mx;
        alpha2[lane + 64] = l2 - mx;
    }
    __syncthreads();
    { f4 av = *(const f4*)&alpha2[ig * 4]; ar0 = av.x; ar1 = av.y; ar2 = av.z; ar3 = av.w; }

    // ---- main chain: 2 steps per iteration, register double-buffer ----
    #pragma unroll 1
    for (int s = 1; s <= 253; s += 2) {
        CRF_STEP(eA0, eA1, eA2, eA3, eB0, eB1, eB2, eB3, s, true)
        CRF_STEP(eB0, eB1, eB2, eB3, eA0, eA1, eA2, eA3, s + 1, true)
    }
    CRF_STEP(eA0, eA1, eA2, eA3, eB0, eB1, eB2, eB3, 255, false)

    // ---- final logsumexp + output ----
    if (w == 0) {
        float f_ = __builtin_amdgcn_exp2f(alpha2[lane]) +
                   __builtin_amdgcn_exp2f(alpha2[lane + 64]);
        #pragma unroll
        for (int off = 32; off; off >>= 1) f_ += __shfl_xor(f_, off);
        if (lane == 0) {
            float logz = (M2 + __builtin_amdgcn_logf(f_)) * LN2f;
            atomicAdd(out, (logz - sgold) / stot);
        }
    }
}

extern "C" void kernel_launch(void* const* d_in, const int* in_sizes, int n_in,
                              void* d_out, int out_size, void* d_ws, size_t ws_size,
                              hipStream_t stream) {
    (void)in_sizes; (void)n_in; (void)out_size; (void)d_ws; (void)ws_size;
    const float* emits = (const float*)d_in[0];
    const int* targets = (const int*)d_in[1];
    const int* mask = (const int*)d_in[2];

    hipMemsetAsync(d_out, 0, sizeof(float), stream);
    hipLaunchKernelGGL(crf_fwd, dim3(NB), dim3(1024), 0, stream,
                       emits, targets, mask, (float*)d_out);
}

// Round 5
// 393.533 us; speedup vs baseline: 2.3287x; 1.6703x over previous
//
#include <hip/hip_runtime.h>

#define NBATCH 16
#define NSEQ 256
#define LO 128
#define NLAB 16384
#define L2E 1.4426950408889634f
#define LN2f 0.6931471805599453f

typedef float f4 __attribute__((ext_vector_type(4)));
typedef float f32x4 __attribute__((ext_vector_type(4)));
typedef short bf16x8 __attribute__((ext_vector_type(8)));
typedef unsigned int u32x4 __attribute__((ext_vector_type(4)));
typedef unsigned short u16x4 __attribute__((ext_vector_type(4)));

__device__ __forceinline__ unsigned short f2bf(float f) {
    unsigned int u = __float_as_uint(f);
    u = (u + 0x7FFFu + ((u >> 16) & 1u)) >> 16;   // RNE
    return (unsigned short)u;
}
__device__ __forceinline__ float bf2f(unsigned short h) {
    return __uint_as_float(((unsigned int)h) << 16);
}
__device__ __forceinline__ void bar_lgkm() {
    asm volatile("s_waitcnt lgkmcnt(0)" ::: "memory");
    __builtin_amdgcn_s_barrier();
}

// LDS byte offset helpers: XOR slot swizzle, slot = (k>>3) ^ (row&15)
__device__ __forceinline__ int soff(int row, int kg) {
    return row * 256 + ((kg ^ (row & 15)) << 4);
}

// ---- one chunk step: fold E_{SS} into (P, M2r). CUR/NXT are f4[8] reg bufs ----
#define PSTEP(CUR, NXT, SS)                                                     \
  {                                                                             \
    if ((SS) + 1 < nst) {                                                       \
      _Pragma("unroll")                                                         \
      for (int r_ = 0; r_ < 8; ++r_)                                            \
        NXT[r_] = ef[(size_t)((SS) + 1) * 4096 + (8 * kgq + r_) * 32 + jcb];    \
    }                                                                           \
    if (maskL[SS]) {                                                            \
      char* qt_ = qtl[qb];                                                      \
      /* Qt-gen: Qt[j][k] = exp2(E*L2E - 16), bf16, swizzled */                 \
      _Pragma("unroll")                                                         \
      for (int jj_ = 0; jj_ < 4; ++jj_) {                                       \
        const int j_ = 4 * jcb + jj_;                                           \
        unsigned int pw_[4];                                                    \
        _Pragma("unroll")                                                       \
        for (int q_ = 0; q_ < 4; ++q_) {                                        \
          float fa_ = __builtin_amdgcn_exp2f(                                   \
              __builtin_fmaf(CUR[2 * q_][jj_], L2E, -16.f));                    \
          float fb_ = __builtin_amdgcn_exp2f(                                   \
              __builtin_fmaf(CUR[2 * q_ + 1][jj_], L2E, -16.f));                \
          pw_[q_] = (unsigned int)f2bf(fa_) |                                   \
                    ((unsigned int)f2bf(fb_) << 16);                            \
        }                                                                       \
        u32x4 pk_; pk_[0]=pw_[0]; pk_[1]=pw_[1]; pk_[2]=pw_[2]; pk_[3]=pw_[3];  \
        *(u32x4*)(qt_ + soff(j_, kgq)) = pk_;                                   \
      }                                                                         \
      bar_lgkm(); /* Qt visible; global prefetch stays in flight */             \
      /* GEMM: C = P(16 rows of this wave) x Q(128x128) */                      \
      bf16x8 a_[4];                                                             \
      _Pragma("unroll")                                                         \
      for (int kk_ = 0; kk_ < 4; ++kk_)                                         \
        a_[kk_] = *(bf16x8*)(pl + soff(ib, kk_ * 4 + lh));                      \
      f32x4 acc_[8];                                                            \
      _Pragma("unroll")                                                         \
      for (int jt_ = 0; jt_ < 8; ++jt_)                                         \
        acc_[jt_] = (f32x4){0.f, 0.f, 0.f, 0.f};                                \
      _Pragma("unroll")                                                         \
      for (int jt_ = 0; jt_ < 8; ++jt_) {                                       \
        const int j_ = jt_ * 16 + li;                                           \
        _Pragma("unroll")                                                       \
        for (int kk_ = 0; kk_ < 4; ++kk_) {                                     \
          bf16x8 b_ = *(bf16x8*)(qt_ + soff(j_, kk_ * 4 + lh));                 \
          acc_[jt_] = __builtin_amdgcn_mfma_f32_16x16x32_bf16(                  \
              a_[kk_], b_, acc_[jt_], 0, 0, 0);                                 \
        }                                                                       \
      }                                                                         \
      /* epilogue: rowmax, renorm to bf16 P', M2r += log2(rmax)+16 */           \
      _Pragma("unroll")                                                         \
      for (int r_ = 0; r_ < 4; ++r_) {                                          \
        float m_ = acc_[0][r_];                                                 \
        _Pragma("unroll")                                                       \
        for (int jt_ = 1; jt_ < 8; ++jt_) m_ = fmaxf(m_, acc_[jt_][r_]);        \
        m_ = fmaxf(m_, __shfl_xor(m_, 1));                                      \
        m_ = fmaxf(m_, __shfl_xor(m_, 2));                                      \
        m_ = fmaxf(m_, __shfl_xor(m_, 4));                                      \
        m_ = fmaxf(m_, __shfl_xor(m_, 8));                                      \
        const float rr_ = 1.0f / m_;                                            \
        M2r[r_] += __builtin_amdgcn_logf(m_) + 16.f;                            \
        const int ir_ = 16 * w + lh * 4 + r_;                                   \
        _Pragma("unroll")                                                       \
        for (int jt_ = 0; jt_ < 8; ++jt_) {                                     \
          const int j_ = jt_ * 16 + li;                                         \
          *(unsigned short*)(pl + soff(ir_, j_ >> 3) + (j_ & 7) * 2) =          \
              f2bf(acc_[jt_][r_] * rr_);                                        \
        }                                                                       \
      }                                                                         \
      qb ^= 1;                                                                  \
    }                                                                           \
  }

// Phase 1: grid 256 (b*16+c), 512 threads. Computes chunk operator (P, M).
__global__ __launch_bounds__(512) void crf_p1(
    const float* __restrict__ emits, const int* __restrict__ mask,
    unsigned short* __restrict__ Pws, float* __restrict__ Mws)
{
    __shared__ char qtl[2][32768];   // double-buffered Qt (bf16, swizzled)
    __shared__ char pl[32768];       // P (bf16, swizzled)
    __shared__ int maskL[16];

    const int b = blockIdx.x >> 4;
    const int c = blockIdx.x & 15;
    const int lo = (c == 0) ? 1 : c * 16;
    const int nst = c * 16 + 16 - lo;     // 15 for c==0, else 16

    const int t = threadIdx.x;
    const int l = t & 63;
    const int w = t >> 6;
    const int li = l & 15;
    const int lh = l >> 4;
    const int ib = 16 * w + li;           // A-frag row
    const int kgq = t >> 5;               // k-group (8 rows) for load/Qt-gen
    const int jcb = t & 31;               // f4 col block

    const f4* ef = (const f4*)emits + ((size_t)b * NSEQ + lo) * 4096;

    f4 e0[8], e1[8];
    #pragma unroll
    for (int r = 0; r < 8; ++r)
        e0[r] = ef[(8 * kgq + r) * 32 + jcb];

    // zero P
    #pragma unroll
    for (int q = 0; q < 4; ++q)
        ((u32x4*)pl)[t * 4 + q] = (u32x4){0u, 0u, 0u, 0u};
    if (t < nst) maskL[t] = mask[b * NSEQ + lo + t];
    __syncthreads();
    // identity diagonal (bf16 1.0 = 0x3F80)
    if (t < 128)
        *(unsigned short*)(pl + soff(t, t >> 3) + (t & 7) * 2) = 0x3F80;
    float M2r[4] = {0.f, 0.f, 0.f, 0.f};
    bar_lgkm();

    int qb = 0;
    #pragma unroll 1
    for (int ss = 0; ss < nst; ss += 2) {
        PSTEP(e0, e1, ss)
        if (ss + 1 < nst) PSTEP(e1, e0, ss + 1)
    }

    bar_lgkm();  // all waves' P' writes visible for export
    // export P: row-major [i][k] bf16 to ws
    {
        const int i = t >> 2, cb = t & 3;
        #pragma unroll
        for (int q = 0; q < 4; ++q) {
            const int kg = cb * 4 + q;
            u32x4 v = *(u32x4*)(pl + soff(i, kg));
            *(u32x4*)(Pws + (size_t)blockIdx.x * 16384 + i * 128 + cb * 32 + q * 8) = v;
        }
    }
    // export M (log2 domain)
    if (li == 0) {
        #pragma unroll
        for (int r = 0; r < 4; ++r)
            Mws[(size_t)blockIdx.x * 128 + 16 * w + lh * 4 + r] = M2r[r];
    }
}

// Phase 2: grid 16 (one per batch), 512 threads. Applies chunk operators to alpha.
__global__ __launch_bounds__(512) void crf_p2(
    const float* __restrict__ emits, const int* __restrict__ targets,
    const int* __restrict__ mask, const unsigned short* __restrict__ Pws,
    const float* __restrict__ Mws, float* __restrict__ out)
{
    __shared__ float alpha2[128];     // log2 domain, shifted
    __shared__ float uvec[128];
    __shared__ float psum[16][128];
    __shared__ float wred[8];
    __shared__ float sStot, sGold;

    const int b = blockIdx.x;
    const int t = threadIdx.x;
    const int l = t & 63;
    const int w = t >> 6;
    const float* eb = emits + (size_t)b * NSEQ * NLAB;

    // total token count (same in every block)
    {
        float cnt = 0.f;
        for (int idx = t; idx < NBATCH * NSEQ; idx += 512)
            cnt += mask[idx] ? 1.f : 0.f;
        #pragma unroll
        for (int off = 32; off; off >>= 1) cnt += __shfl_xor(cnt, off);
        if (l == 0) wred[w] = cnt;
    }
    __syncthreads();
    if (t == 0) {
        float s = 0.f;
        #pragma unroll
        for (int k = 0; k < 8; ++k) s += wred[k];
        sStot = s;
    }
    __syncthreads();
    // gold score for this batch
    {
        float g = 0.f;
        if (t < NSEQ && mask[b * NSEQ + t])
            g = eb[(size_t)t * NLAB + targets[b * NSEQ + t]];
        #pragma unroll
        for (int off = 32; off; off >>= 1) g += __shfl_xor(g, off);
        if (l == 0 && w < 4) wred[w] = g;
    }
    // alpha init: E_0[BOS=0][j] in log2 domain
    if (t < 128) alpha2[t] = eb[t] * L2E;
    __syncthreads();
    if (t == 0) sGold = wred[0] + wred[1] + wred[2] + wred[3];

    float Mal = 0.f;
    const int ig = t >> 5;        // 16 groups of 8 rows
    const int j4 = (t & 31) * 4;  // 4-col block

    #pragma unroll 1
    for (int c = 0; c < 16; ++c) {
        const unsigned short* Pr = Pws + (size_t)(b * 16 + c) * 16384;
        const float* Mr = Mws + (size_t)(b * 16 + c) * 128;
        // issue P row loads early (independent of u)
        u16x4 pv[8];
        #pragma unroll
        for (int r = 0; r < 8; ++r)
            pv[r] = *(const u16x4*)(Pr + (ig * 8 + r) * 128 + j4);

        // phase A: a = alpha2 + Mc, blockwise max
        float av = 0.f;
        if (t < 128) {
            av = alpha2[t] + Mr[t];
            float mx = av;
            #pragma unroll
            for (int off = 32; off; off >>= 1) mx = fmaxf(mx, __shfl_xor(mx, off));
            if (l == 0) wred[w] = mx;
        }
        __syncthreads();
        if (t < 128) {
            const float mx = fmaxf(wred[0], wred[1]);
            Mal += mx;
            uvec[t] = __builtin_amdgcn_exp2f(av - mx);
        }
        __syncthreads();
        // phase B: partial matvec psum[ig][j] = sum_{i in group} u[i]*P[i][j]
        {
            f4 ps = (f4){0.f, 0.f, 0.f, 0.f};
            #pragma unroll
            for (int r = 0; r < 8; ++r) {
                const float uu = uvec[ig * 8 + r];
                ps[0] = __builtin_fmaf(uu, bf2f(pv[r][0]), ps[0]);
                ps[1] = __builtin_fmaf(uu, bf2f(pv[r][1]), ps[1]);
                ps[2] = __builtin_fmaf(uu, bf2f(pv[r][2]), ps[2]);
                ps[3] = __builtin_fmaf(uu, bf2f(pv[r][3]), ps[3]);
            }
            *(f4*)&psum[ig][j4] = ps;
        }
        __syncthreads();
        // phase C: combine + log2
        if (t < 128) {
            float v = 0.f;
            #pragma unroll
            for (int g = 0; g < 16; ++g) v += psum[g][t];
            alpha2[t] = __builtin_amdgcn_logf(v);
        }
        __syncthreads();
    }

    // final logsumexp (alpha2 <= 7 always; no shift needed)
    {
        float e = (t < 128) ? __builtin_amdgcn_exp2f(alpha2[t]) : 0.f;
        if (t < 128) {
            #pragma unroll
            for (int off = 32; off; off >>= 1) e += __shfl_xor(e, off);
            if (l == 0) wred[w] = e;
        }
        __syncthreads();
        if (t == 0) {
            const float logz = (Mal + __builtin_amdgcn_logf(wred[0] + wred[1])) * LN2f;
            atomicAdd(out, (logz - sGold) / sStot);
        }
    }
}

extern "C" void kernel_launch(void* const* d_in, const int* in_sizes, int n_in,
                              void* d_out, int out_size, void* d_ws, size_t ws_size,
                              hipStream_t stream) {
    (void)in_sizes; (void)n_in; (void)out_size; (void)ws_size;
    const float* emits = (const float*)d_in[0];
    const int* targets = (const int*)d_in[1];
    const int* mask = (const int*)d_in[2];
    unsigned short* Pws = (unsigned short*)d_ws;                       // 8 MB
    float* Mws = (float*)((char*)d_ws + (size_t)16384 * 256 * 2);      // +128 KB

    hipMemsetAsync(d_out, 0, sizeof(float), stream);
    hipLaunchKernelGGL(crf_p1, dim3(256), dim3(512), 0, stream, emits, mask, Pws, Mws);
    hipLaunchKernelGGL(crf_p2, dim3(16), dim3(512), 0, stream, emits, targets, mask,
                       Pws, Mws, (float*)d_out);
}

// Round 8
// 382.597 us; speedup vs baseline: 2.3952x; 1.0286x over previous
//
#include <hip/hip_runtime.h>

#define NBATCH 16
#define NSEQ 256
#define LO 128
#define NLAB 16384
#define L2E 1.4426950408889634f
#define LN2f 0.6931471805599453f

typedef float f4 __attribute__((ext_vector_type(4)));
typedef float f32x4 __attribute__((ext_vector_type(4)));
typedef short bf16x8 __attribute__((ext_vector_type(8)));
typedef unsigned int u32x4 __attribute__((ext_vector_type(4)));
typedef unsigned short u16x4 __attribute__((ext_vector_type(4)));

__device__ __forceinline__ float bf2f(unsigned short h) {
    return __uint_as_float(((unsigned int)h) << 16);
}
__device__ __forceinline__ unsigned int cvt_pk_bf16(float a, float b) {
    unsigned int r;  // lo = bf16(a), hi = bf16(b)
    asm("v_cvt_pk_bf16_f32 %0, %1, %2" : "=v"(r) : "v"(a), "v"(b));
    return r;
}
__device__ __forceinline__ void bar_lgkm() {
    asm volatile("s_waitcnt lgkmcnt(0)" ::: "memory");
    __builtin_amdgcn_s_barrier();
}

// LDS byte offset: slot = kg ^ (row&15) ^ (row>>4 & 7)
// reads (16 rows, li-varying): 16 distinct slots -> 2-way (free)
// Qt-gen writes (rows stride 4 over 32 lanes): 2 lanes/slot -> 2-way (free)
__device__ __forceinline__ int soff(int row, int kg) {
    return row * 256 + ((kg ^ (row & 15) ^ ((row >> 4) & 7)) << 4);
}

// ---- one chunk step: fold E_{SS} into P (no renorm; M += 8 per applied step) ----
#define PSTEP(CUR, NXT, SS)                                                     \
  {                                                                             \
    if ((SS) + 1 < nst) {                                                       \
      _Pragma("unroll")                                                         \
      for (int r_ = 0; r_ < 8; ++r_)                                            \
        NXT[r_] = ef[(size_t)((SS) + 1) * 4096 + (8 * kgq + r_) * 32 + jcb];    \
    }                                                                           \
    if (maskL[SS]) {                                                            \
      char* qt_ = qtl[qb];                                                      \
      /* Qt-gen: Qt[j][k] = exp2(E*L2E - 8), bf16, swizzled */                  \
      _Pragma("unroll")                                                         \
      for (int jj_ = 0; jj_ < 4; ++jj_) {                                       \
        const int j_ = 4 * jcb + jj_;                                           \
        unsigned int pw_[4];                                                    \
        _Pragma("unroll")                                                       \
        for (int q_ = 0; q_ < 4; ++q_) {                                        \
          float fa_ = __builtin_amdgcn_exp2f(                                   \
              __builtin_fmaf(CUR[2 * q_][jj_], L2E, -8.f));                     \
          float fb_ = __builtin_amdgcn_exp2f(                                   \
              __builtin_fmaf(CUR[2 * q_ + 1][jj_], L2E, -8.f));                 \
          pw_[q_] = cvt_pk_bf16(fa_, fb_);                                      \
        }                                                                       \
        u32x4 pk_; pk_[0]=pw_[0]; pk_[1]=pw_[1]; pk_[2]=pw_[2]; pk_[3]=pw_[3];  \
        *(u32x4*)(qt_ + soff(j_, kgq)) = pk_;                                   \
      }                                                                         \
      bar_lgkm(); /* B1: Qt + prior epilogue visible; global prefetch in flight */ \
      /* GEMM: wave computes rows [32rb,32rb+32) x cols [64jh,64jh+64) */       \
      f32x4 acc_[2][4];                                                         \
      _Pragma("unroll")                                                         \
      for (int ri_ = 0; ri_ < 2; ++ri_)                                         \
        _Pragma("unroll")                                                       \
        for (int jt_ = 0; jt_ < 4; ++jt_)                                       \
          acc_[ri_][jt_] = (f32x4){0.f, 0.f, 0.f, 0.f};                         \
      _Pragma("unroll")                                                         \
      for (int kk_ = 0; kk_ < 4; ++kk_) {                                       \
        bf16x8 a0_ = *(bf16x8*)(pl + soff(ib0, kk_ * 4 + lh));                  \
        bf16x8 a1_ = *(bf16x8*)(pl + soff(ib1, kk_ * 4 + lh));                  \
        _Pragma("unroll")                                                       \
        for (int jt_ = 0; jt_ < 4; ++jt_) {                                     \
          bf16x8 b_ = *(bf16x8*)(qt_ + soff(jb0 + jt_ * 16 + li, kk_ * 4 + lh));\
          acc_[0][jt_] = __builtin_amdgcn_mfma_f32_16x16x32_bf16(               \
              a0_, b_, acc_[0][jt_], 0, 0, 0);                                  \
          acc_[1][jt_] = __builtin_amdgcn_mfma_f32_16x16x32_bf16(               \
              a1_, b_, acc_[1][jt_], 0, 0, 0);                                  \
        }                                                                       \
      }                                                                         \
      bar_lgkm(); /* B2: all waves done reading P rows before overwrite */      \
      /* epilogue: P' = C (bf16), no renorm */                                  \
      _Pragma("unroll")                                                         \
      for (int ri_ = 0; ri_ < 2; ++ri_) {                                       \
        _Pragma("unroll")                                                       \
        for (int r_ = 0; r_ < 4; ++r_) {                                        \
          const int ir_ = 32 * rb + 16 * ri_ + lh * 4 + r_;                     \
          _Pragma("unroll")                                                     \
          for (int jp_ = 0; jp_ < 2; ++jp_) {                                   \
            const int j0_ = jb0 + jp_ * 32 + li;                                \
            const unsigned int pk_ = cvt_pk_bf16(acc_[ri_][2 * jp_][r_],        \
                                                 acc_[ri_][2 * jp_ + 1][r_]);   \
            *(unsigned short*)(pl + soff(ir_, j0_ >> 3) + (j0_ & 7) * 2) =      \
                (unsigned short)pk_;                                            \
            const int j1_ = j0_ + 16;                                           \
            *(unsigned short*)(pl + soff(ir_, j1_ >> 3) + (j1_ & 7) * 2) =      \
                (unsigned short)(pk_ >> 16);                                    \
          }                                                                     \
        }                                                                       \
      }                                                                         \
      qb ^= 1;                                                                  \
    }                                                                           \
  }

// Phase 1: grid 256 (b*16+c), 512 threads. Computes chunk operator (P, M-scalar).
__global__ __launch_bounds__(512) void crf_p1(
    const float* __restrict__ emits, const int* __restrict__ mask,
    unsigned short* __restrict__ Pws, float* __restrict__ Mws)
{
    __shared__ char qtl[2][32768];   // double-buffered Qt (bf16, swizzled)
    __shared__ char pl[32768];       // P (bf16, swizzled)
    __shared__ int maskL[16];

    const int b = blockIdx.x >> 4;
    const int c = blockIdx.x & 15;
    const int lo = (c == 0) ? 1 : c * 16;
    const int nst = c * 16 + 16 - lo;     // 15 for c==0, else 16

    const int t = threadIdx.x;
    const int l = t & 63;
    const int w = t >> 6;
    const int li = l & 15;
    const int lh = l >> 4;
    const int rb = w >> 1;                // row band 0..3 (32 rows)
    const int jh = w & 1;                 // col half 0..1 (64 cols)
    const int ib0 = 32 * rb + li;
    const int ib1 = ib0 + 16;
    const int jb0 = 64 * jh;
    const int kgq = t >> 5;               // k-group (8 rows) for load/Qt-gen
    const int jcb = t & 31;               // f4 col block

    const f4* ef = (const f4*)emits + ((size_t)b * NSEQ + lo) * 4096;

    f4 e0[8], e1[8];
    #pragma unroll
    for (int r = 0; r < 8; ++r)
        e0[r] = ef[(8 * kgq + r) * 32 + jcb];

    // zero P + stage mask
    #pragma unroll
    for (int q = 0; q < 4; ++q)
        ((u32x4*)pl)[t * 4 + q] = (u32x4){0u, 0u, 0u, 0u};
    if (t < nst) maskL[t] = mask[b * NSEQ + lo + t];
    __syncthreads();
    // identity diagonal (bf16 1.0 = 0x3F80)
    if (t < 128)
        *(unsigned short*)(pl + soff(t, t >> 3) + (t & 7) * 2) = 0x3F80;
    bar_lgkm();

    int qb = 0;
    #pragma unroll 1
    for (int ss = 0; ss < nst; ss += 2) {
        PSTEP(e0, e1, ss)
        if (ss + 1 < nst) PSTEP(e1, e0, ss + 1)
    }

    bar_lgkm();  // all waves' P' writes visible for export
    // export P: row-major [i][k] bf16 to ws
    {
        const int i = t >> 2, cb = t & 3;
        #pragma unroll
        for (int q = 0; q < 4; ++q) {
            const int kg = cb * 4 + q;
            u32x4 v = *(u32x4*)(pl + soff(i, kg));
            *(u32x4*)(Pws + (size_t)blockIdx.x * 16384 + i * 128 + cb * 32 + q * 8) = v;
        }
    }
    // export M (log2 domain, scalar per chunk): 8 per applied step
    if (t == 0) {
        int ms = 0;
        for (int s = 0; s < nst; ++s) ms += maskL[s] ? 1 : 0;
        Mws[blockIdx.x] = 8.f * (float)ms;
    }
}

// Phase 2: grid 16 (one per batch), 512 threads. Applies chunk operators to alpha.
__global__ __launch_bounds__(512) void crf_p2(
    const float* __restrict__ emits, const int* __restrict__ targets,
    const int* __restrict__ mask, const unsigned short* __restrict__ Pws,
    const float* __restrict__ Mws, float* __restrict__ out)
{
    __shared__ float alpha2[128];     // log2 domain
    __shared__ float uvec[128];
    __shared__ float psum[16][128];
    __shared__ float wred[8];
    __shared__ float sStot, sGold;

    const int b = blockIdx.x;
    const int t = threadIdx.x;
    const int l = t & 63;
    const int w = t >> 6;
    const float* eb = emits + (size_t)b * NSEQ * NLAB;

    // total token count (same in every block)
    {
        float cnt = 0.f;
        for (int idx = t; idx < NBATCH * NSEQ; idx += 512)
            cnt += mask[idx] ? 1.f : 0.f;
        #pragma unroll
        for (int off = 32; off; off >>= 1) cnt += __shfl_xor(cnt, off);
        if (l == 0) wred[w] = cnt;
    }
    __syncthreads();
    if (t == 0) {
        float s = 0.f;
        #pragma unroll
        for (int k = 0; k < 8; ++k) s += wred[k];
        sStot = s;
    }
    __syncthreads();
    // gold score for this batch
    {
        float g = 0.f;
        if (t < NSEQ && mask[b * NSEQ + t])
            g = eb[(size_t)t * NLAB + targets[b * NSEQ + t]];
        #pragma unroll
        for (int off = 32; off; off >>= 1) g += __shfl_xor(g, off);
        if (l == 0 && w < 4) wred[w] = g;
    }
    // alpha init: E_0[BOS=0][j] in log2 domain
    if (t < 128) alpha2[t] = eb[t] * L2E;
    __syncthreads();
    if (t == 0) sGold = wred[0] + wred[1] + wred[2] + wred[3];
    __syncthreads();

    float Mal = 0.f;
    const int ig = t >> 5;        // 16 groups of 8 rows
    const int j4 = (t & 31) * 4;  // 4-col block

    #pragma unroll 1
    for (int c = 0; c < 16; ++c) {
        const unsigned short* Pr = Pws + (size_t)(b * 16 + c) * 16384;
        const float Mc = Mws[b * 16 + c];
        // issue P row loads early (independent of u)
        u16x4 pv[8];
        #pragma unroll
        for (int r = 0; r < 8; ++r)
            pv[r] = *(const u16x4*)(Pr + (ig * 8 + r) * 128 + j4);

        // phase A: blockwise max of alpha2
        float av = 0.f;
        if (t < 128) {
            av = alpha2[t];
            float mx = av;
            #pragma unroll
            for (int off = 32; off; off >>= 1) mx = fmaxf(mx, __shfl_xor(mx, off));
            if (l == 0) wred[w] = mx;
        }
        __syncthreads();
        if (t < 128) {
            const float mx = fmaxf(wred[0], wred[1]);
            Mal += Mc + mx;
            uvec[t] = __builtin_amdgcn_exp2f(av - mx);
        }
        __syncthreads();
        // phase B: partial matvec psum[ig][j] = sum_{i in group} u[i]*P[i][j]
        {
            f4 ps = (f4){0.f, 0.f, 0.f, 0.f};
            #pragma unroll
            for (int r = 0; r < 8; ++r) {
                const float uu = uvec[ig * 8 + r];
                ps[0] = __builtin_fmaf(uu, bf2f(pv[r][0]), ps[0]);
                ps[1] = __builtin_fmaf(uu, bf2f(pv[r][1]), ps[1]);
                ps[2] = __builtin_fmaf(uu, bf2f(pv[r][2]), ps[2]);
                ps[3] = __builtin_fmaf(uu, bf2f(pv[r][3]), ps[3]);
            }
            *(f4*)&psum[ig][j4] = ps;
        }
        __syncthreads();
        // phase C: combine + log2 (same-thread write; no barrier before next A)
        if (t < 128) {
            float v = 0.f;
            #pragma unroll
            for (int g = 0; g < 16; ++g) v += psum[g][t];
            alpha2[t] = __builtin_amdgcn_logf(v);
        }
    }
    __syncthreads();

    // final logsumexp (alpha2 bounded ~ +/-100 in log2 -> direct exp2 safe)
    {
        float e = (t < 128) ? __builtin_amdgcn_exp2f(alpha2[t]) : 0.f;
        if (t < 128) {
            #pragma unroll
            for (int off = 32; off; off >>= 1) e += __shfl_xor(e, off);
            if (l == 0) wred[w] = e;
        }
        __syncthreads();
        if (t == 0) {
            const float logz = (Mal + __builtin_amdgcn_logf(wred[0] + wred[1])) * LN2f;
            atomicAdd(out, (logz - sGold) / sStot);
        }
    }
}

extern "C" void kernel_launch(void* const* d_in, const int* in_sizes, int n_in,
                              void* d_out, int out_size, void* d_ws, size_t ws_size,
                              hipStream_t stream) {
    (void)in_sizes; (void)n_in; (void)out_size; (void)ws_size;
    const float* emits = (const float*)d_in[0];
    const int* targets = (const int*)d_in[1];
    const int* mask = (const int*)d_in[2];
    unsigned short* Pws = (unsigned short*)d_ws;                       // 8 MB
    float* Mws = (float*)((char*)d_ws + (size_t)16384 * 256 * 2);      // +1 KB

    hipMemsetAsync(d_out, 0, sizeof(float), stream);
    hipLaunchKernelGGL(crf_p1, dim3(256), dim3(512), 0, stream, emits, mask, Pws, Mws);
    hipLaunchKernelGGL(crf_p2, dim3(16), dim3(512), 0, stream, emits, targets, mask,
                       Pws, Mws, (float*)d_out);
}